// Round 1
// baseline (452.689 us; speedup 1.0000x reference)
//
#include <hip/hip_runtime.h>
#include <stdint.h>

// Problem dims (fixed by the reference): B=2048, T=512, F=64, H=16, 4H=64.
#define Bdim 2048
#define Tdim 512
#define TT 8                    // timesteps per staged tile
#define NT (Tdim / TT)          // 64 tiles

// LDS x staging: [buf 2][b 16][t 8][f 64] fp32, +4 dword pad per b-row.
#define XSTR (TT * 64 + 4)      // 516 dwords per batch row
#define XBUF (16 * XSTR)        // 8256 dwords per buffer (33 KB)
// LDS z staging: [buf 2][t 8][b 16][c 64] fp32, +4 dword pad per b-row.
#define ZSTR 68                 // dwords per batch row (64 + 4 pad)
#define ZTS  (16 * ZSTR)        // 1088 dwords per timestep
#define ZBUF (TT * ZTS)         // 8704 dwords per buffer (34 KB)

typedef __attribute__((ext_vector_type(8))) short bf16x8;   // 8 bf16, 4 VGPRs
typedef __attribute__((ext_vector_type(4))) float f32x4;

union U32x4 { uint32_t u[4]; bf16x8 v; };

__device__ __forceinline__ uint16_t f2bf(float f) {
    // round-to-nearest-even fp32 -> bf16
    union { float f; uint32_t u; } v; v.f = f;
    uint32_t r = v.u + 0x7fffu + ((v.u >> 16) & 1u);
    return (uint16_t)(r >> 16);
}
__device__ __forceinline__ float sigmoidf(float z) {
    return __builtin_amdgcn_rcpf(1.0f + __expf(-z));
}
__device__ __forceinline__ float fast_exp2(float x) {
#if __has_builtin(__builtin_amdgcn_exp2f)
    return __builtin_amdgcn_exp2f(x);
#else
    return exp2f(x);
#endif
}
__device__ __forceinline__ void gld16(const float* gsrc, float* ldst) {
    // 16B per lane, dest = wave-uniform LDS base + lane*16 (HW rule).
    __builtin_amdgcn_global_load_lds(
        (__attribute__((address_space(1))) void*)(gsrc),
        (__attribute__((address_space(3))) void*)(ldst), 16, 0, 0);
}

// 128 blocks x 128 threads. Wave 0 = scan (16 batch rows via swapped-operand
// MFMA recurrence, zero cross-lane traffic per step). Wave 1 = producer
// (global_load_lds x staging + xz^T = Wx^T x^T MFMA projection into LDS,
// double-buffered, one barrier per 8-step tile).
//
// Layout identity that removes all shuffles: with z^T = Wh^T h^T computed as
// mfma(A=Wh^T frag, B=h^T frag, C=xz^T), lane (q=lane>>4, j=lane&15) gets
// D[row=q*4+r][col=j] = z[b=j][gate nt][unit q*4+r]. All 4 gates of unit
// u=q*4+r are lane-local -> c,h update local. h[b=j][u=q*4+r] is EXACTLY the
// B-fragment slot k=q*8+r (slots q*8+4..7 zero, mirrored by zero rows in the
// Wh A-fragment) -> next step's MFMA B operand with no data movement.
__global__ __launch_bounds__(128, 1) void lstm_fused(
    const float* __restrict__ x, const float* __restrict__ Wx,
    const float* __restrict__ bias, const float* __restrict__ Wh,
    const float* __restrict__ W2, const float* __restrict__ b2,
    const float* __restrict__ W3, const float* __restrict__ b3,
    const float* __restrict__ Wo, const float* __restrict__ bo,
    float* __restrict__ out)
{
    __shared__ __align__(16) float xlds[2 * XBUF];   // 66048 B
    __shared__ __align__(16) float zbuf[2 * ZBUF];   // 69632 B
    __shared__ __align__(16) float hlds[16 * 17];    // head staging

    const int lane = threadIdx.x & 63;
    const int wid  = threadIdx.x >> 6;    // 0 = scan, 1 = producer
    const int q = lane >> 4;
    const int j = lane & 15;
    const int b0 = blockIdx.x * 16;
    const float KLOG2E = 1.4426950408889634f;

    // ---- producer state: Wx^T A-fragments (gate-scaled), scaled bias ----
    bf16x8 awx[4][2];
    f32x4  bcol[4];
    // ---- scan state: Wh^T A-fragments (zero-padded K), c, h ----
    bf16x8 awh[4];
    float  cst[4] = {0.f, 0.f, 0.f, 0.f};
    float  hh[4]  = {0.f, 0.f, 0.f, 0.f};
    uint32_t hw0 = 0, hw1 = 0;            // packed bf16 h (B-frag regs 0,1)

    auto gload = [&](int tile, int buf) {
        // 16 b-rows x 2 KB contiguous each; 2x 1KB global_load_lds per row.
        const float* src0 = x + ((size_t)b0 * Tdim + tile * TT) * 64 + lane * 4;
        #pragma unroll
        for (int rb = 0; rb < 16; ++rb) {
            const float* s = src0 + (size_t)rb * Tdim * 64;
            float* d = &xlds[buf * XBUF + rb * XSTR];
            gld16(s, d);
            gld16(s + 256, d + 256);
        }
    };

    auto proj = [&](int srcbuf, int dstbuf) {
        // z^T_t = Wx^T x^T_t (+ scaled bias), 8 MFMA 16x16x32 per t.
        const float* xb = &xlds[srcbuf * XBUF] + j * XSTR + q * 8;
        float* zb = &zbuf[dstbuf * ZBUF] + j * ZSTR + q * 4;
        #pragma unroll
        for (int t = 0; t < TT; ++t) {
            const float* px = xb + t * 64;
            f32x4 x0 = *(const f32x4*)(px);
            f32x4 x1 = *(const f32x4*)(px + 4);
            f32x4 x2 = *(const f32x4*)(px + 32);
            f32x4 x3 = *(const f32x4*)(px + 36);
            U32x4 bx0, bx1;
            asm("v_cvt_pk_bf16_f32 %0, %1, %2" : "=v"(bx0.u[0]) : "v"(x0[0]), "v"(x0[1]));
            asm("v_cvt_pk_bf16_f32 %0, %1, %2" : "=v"(bx0.u[1]) : "v"(x0[2]), "v"(x0[3]));
            asm("v_cvt_pk_bf16_f32 %0, %1, %2" : "=v"(bx0.u[2]) : "v"(x1[0]), "v"(x1[1]));
            asm("v_cvt_pk_bf16_f32 %0, %1, %2" : "=v"(bx0.u[3]) : "v"(x1[2]), "v"(x1[3]));
            asm("v_cvt_pk_bf16_f32 %0, %1, %2" : "=v"(bx1.u[0]) : "v"(x2[0]), "v"(x2[1]));
            asm("v_cvt_pk_bf16_f32 %0, %1, %2" : "=v"(bx1.u[1]) : "v"(x2[2]), "v"(x2[3]));
            asm("v_cvt_pk_bf16_f32 %0, %1, %2" : "=v"(bx1.u[2]) : "v"(x3[0]), "v"(x3[1]));
            asm("v_cvt_pk_bf16_f32 %0, %1, %2" : "=v"(bx1.u[3]) : "v"(x3[2]), "v"(x3[3]));
            #pragma unroll
            for (int nt = 0; nt < 4; ++nt) {
                f32x4 a = bcol[nt];
                a = __builtin_amdgcn_mfma_f32_16x16x32_bf16(awx[nt][0], bx0.v, a, 0, 0, 0);
                a = __builtin_amdgcn_mfma_f32_16x16x32_bf16(awx[nt][1], bx1.v, a, 0, 0, 0);
                *(f32x4*)(zb + t * ZTS + nt * 16) = a;
            }
        }
    };

    if (wid == 1) {
        // A[m=j][k=q*8+jj] = Wx^T[c=nt*16+j][f=kc*32+q*8+jj], scaled by
        // -log2(e) for sigmoid gates (i,f,o) so sigma = rcp(1+exp2(w)).
        #pragma unroll
        for (int nt = 0; nt < 4; ++nt) {
            const float s = (nt == 2) ? 1.0f : -KLOG2E;
            #pragma unroll
            for (int kc = 0; kc < 2; ++kc)
                #pragma unroll
                for (int jj = 0; jj < 8; ++jj)
                    awx[nt][kc][jj] = (short)f2bf(
                        Wx[(size_t)(kc * 32 + q * 8 + jj) * 64 + nt * 16 + j] * s);
            #pragma unroll
            for (int r = 0; r < 4; ++r)
                bcol[nt][r] = bias[nt * 16 + q * 4 + r] * s;
        }
        gload(0, 0);
        asm volatile("s_waitcnt vmcnt(0)" ::: "memory");
    } else {
        // A[m=j][k=q*8+jj] = Wh[unit q*4+jj][c=nt*16+j] for jj<4, else 0.
        #pragma unroll
        for (int nt = 0; nt < 4; ++nt) {
            const float s = (nt == 2) ? 1.0f : -KLOG2E;
            bf16x8 a;
            #pragma unroll
            for (int e = 0; e < 8; ++e) a[e] = 0;
            #pragma unroll
            for (int e = 0; e < 4; ++e)
                a[e] = (short)f2bf(Wh[(size_t)(q * 4 + e) * 64 + nt * 16 + j] * s);
            awh[nt] = a;
        }
    }
    __syncthreads();                       // x tile 0 resident
    if (wid == 1) {
        gload(1, 1);                       // tile 1 in flight under proj(0)
        proj(0, 0);                        // zbuf[0] = xz^T tile 0
        asm volatile("s_waitcnt vmcnt(0) lgkmcnt(0)" ::: "memory");
    }
    __syncthreads();                       // zbuf[0] + x tile 1 resident

    for (int n = 0; n < NT; ++n) {
        if (wid == 0) {
            const float* zp = &zbuf[(n & 1) * ZBUF] + j * ZSTR + q * 4;
            f32x4 zc0 = *(const f32x4*)(zp);
            f32x4 zc1 = *(const f32x4*)(zp + 16);
            f32x4 zc2 = *(const f32x4*)(zp + 32);
            f32x4 zc3 = *(const f32x4*)(zp + 48);
            #pragma unroll
            for (int t = 0; t < TT; ++t) {
                f32x4 zn0, zn1, zn2, zn3;
                if (t < TT - 1) {          // prefetch next step's z
                    const float* zq = zp + (t + 1) * ZTS;
                    zn0 = *(const f32x4*)(zq);
                    zn1 = *(const f32x4*)(zq + 16);
                    zn2 = *(const f32x4*)(zq + 32);
                    zn3 = *(const f32x4*)(zq + 48);
                }
                U32x4 hbu; hbu.u[0] = hw0; hbu.u[1] = hw1; hbu.u[2] = 0; hbu.u[3] = 0;
                f32x4 ai = __builtin_amdgcn_mfma_f32_16x16x32_bf16(awh[0], hbu.v, zc0, 0, 0, 0);
                f32x4 af = __builtin_amdgcn_mfma_f32_16x16x32_bf16(awh[1], hbu.v, zc1, 0, 0, 0);
                f32x4 ag = __builtin_amdgcn_mfma_f32_16x16x32_bf16(awh[2], hbu.v, zc2, 0, 0, 0);
                f32x4 ao = __builtin_amdgcn_mfma_f32_16x16x32_bf16(awh[3], hbu.v, zc3, 0, 0, 0);
                #pragma unroll
                for (int r = 0; r < 4; ++r) {
                    // ai/af/ao hold w = -z*log2e; sigma = rcp(1+2^w).
                    float si = __builtin_amdgcn_rcpf(1.0f + fast_exp2(ai[r]));
                    float sf = __builtin_amdgcn_rcpf(1.0f + fast_exp2(af[r]));
                    float so = __builtin_amdgcn_rcpf(1.0f + fast_exp2(ao[r]));
                    float gg = fmaxf(ag[r], 0.0f);
                    cst[r] = fmaf(sf, cst[r], si * gg);
                    hh[r] = so * fmaxf(cst[r], 0.0f);   // h = o * relu(c_new)
                }
                asm("v_cvt_pk_bf16_f32 %0, %1, %2" : "=v"(hw0) : "v"(hh[0]), "v"(hh[1]));
                asm("v_cvt_pk_bf16_f32 %0, %1, %2" : "=v"(hw1) : "v"(hh[2]), "v"(hh[3]));
                if (t < TT - 1) { zc0 = zn0; zc1 = zn1; zc2 = zn2; zc3 = zn3; }
            }
        } else {
            if (n + 2 < NT) gload(n + 2, n & 1);          // overlaps proj
            if (n + 1 < NT) proj((n + 1) & 1, (n + 1) & 1);
            asm volatile("s_waitcnt vmcnt(0) lgkmcnt(0)" ::: "memory");
        }
        __syncthreads();
    }

    // ---- MLP head: gather h_T (f32) via LDS, 16 lanes finish rows ----
    if (wid == 0) {
        #pragma unroll
        for (int r = 0; r < 4; ++r) hlds[j * 17 + q * 4 + r] = hh[r];
        // same-wave DS ordering: writes precede reads in program order
        if (lane < 16) {
            const float* hp = &hlds[lane * 17];
            float x2[8];
            #pragma unroll
            for (int k = 0; k < 8; ++k) {
                float s = b2[k];
                #pragma unroll
                for (int u = 0; u < 16; ++u) s = fmaf(hp[u], W2[(size_t)u * 8 + k], s);
                x2[k] = fmaxf(s, 0.f);
            }
            float x3[4];
            #pragma unroll
            for (int m = 0; m < 4; ++m) {
                float s = b3[m];
                #pragma unroll
                for (int k = 0; k < 8; ++k) s = fmaf(x2[k], W3[(size_t)k * 4 + m], s);
                x3[m] = fmaxf(s, 0.f);
            }
            float s = bo[0];
            #pragma unroll
            for (int m = 0; m < 4; ++m) s = fmaf(x3[m], Wo[m], s);
            out[b0 + lane] = sigmoidf(s);
        }
    }
}

extern "C" void kernel_launch(void* const* d_in, const int* in_sizes, int n_in,
                              void* d_out, int out_size, void* d_ws, size_t ws_size,
                              hipStream_t stream) {
    const float* x  = (const float*)d_in[0];
    const float* Wx = (const float*)d_in[1];
    const float* Wh = (const float*)d_in[2];
    const float* bb = (const float*)d_in[3];
    const float* W2 = (const float*)d_in[4];
    const float* b2 = (const float*)d_in[5];
    const float* W3 = (const float*)d_in[6];
    const float* b3 = (const float*)d_in[7];
    const float* Wo = (const float*)d_in[8];
    const float* bo = (const float*)d_in[9];

    // 16 batch rows per block: scan wave + producer wave.
    lstm_fused<<<Bdim / 16, 128, 0, stream>>>(x, Wx, bb, Wh, W2, b2, W3, b3,
                                              Wo, bo, (float*)d_out);
}

// Round 4
// 424.993 us; speedup vs baseline: 1.0652x; 1.0652x over previous
//
#include <hip/hip_runtime.h>
#include <stdint.h>

// Problem dims (fixed by the reference): B=2048, T=512, F=64, H=16, 4H=64.
#define Bdim 2048
#define Tdim 512
#define NTILE 32                 // 32 tiles of 16 timesteps

typedef __attribute__((ext_vector_type(8))) short bf16x8;   // 8 bf16, 4 VGPRs
typedef __attribute__((ext_vector_type(4))) float f32x4;

union U32x4 { uint32_t u[4]; bf16x8 v; };

__device__ __forceinline__ uint16_t f2bf(float f) {
    union { float f; uint32_t u; } v; v.f = f;
    uint32_t r = v.u + 0x7fffu + ((v.u >> 16) & 1u);
    return (uint16_t)(r >> 16);
}
__device__ __forceinline__ float sigmoidf(float z) {
    return __builtin_amdgcn_rcpf(1.0f + __expf(-z));
}
__device__ __forceinline__ float fast_exp2(float x) {
#if __has_builtin(__builtin_amdgcn_exp2f)
    return __builtin_amdgcn_exp2f(x);
#else
    return exp2f(x);
#endif
}

// DPP row-rotate within each 16-lane row. Direction is never assumed: the
// weight permutation is derived at init by applying the SAME op to lane idx.
#define RORF(M, dst, src)                                                     \
    dst = __int_as_float(__builtin_amdgcn_update_dpp(                         \
        __float_as_int(src), __float_as_int(src), 0x120 | (M), 0xF, 0xF, 0))
#define RORI(M, dst, src)                                                     \
    dst = __builtin_amdgcn_update_dpp((src), (src), 0x120 | (M), 0xF, 0xF, 0)

// 2048 single-wave blocks, one batch row per wave (8 waves/CU, no barriers).
// Lane (quad g, u = lane&15) owns gate g of hidden unit u (col = g*16+u).
// Per step:
//   - recurrent dot: 16 fma with DPP row_ror'd h (h distributed: lane holds
//     h[u], identical across the 4 quads) -- zero LDS, zero shuffles
//   - activation: sigmoid lanes pre-scaled by -log2e -> rcp(1+exp2(acc))
//   - gate gather: 3 __shfl_xor (DS pipe, ~3 ops/step vs round-0's ~10)
//   - role sort: 8 cndmask with loop-invariant masks
// xz = x@Wx + b is produced per-wave by MFMA (A = 16-timestep x tile,
// B = Wx frags) into a double-buffered LDS tile laid out [tb][col][4] so both
// the b128 store and the 1-read-per-4-steps are bank-uniform.
__global__ __launch_bounds__(64, 2) void lstm_fused(
    const float* __restrict__ x, const float* __restrict__ Wx,
    const float* __restrict__ bias, const float* __restrict__ Wh,
    const float* __restrict__ W2, const float* __restrict__ b2,
    const float* __restrict__ W3, const float* __restrict__ b3,
    const float* __restrict__ Wo, const float* __restrict__ bo,
    float* __restrict__ out)
{
    __shared__ __align__(16) float zbuf[2048];   // [2 buf][4 tb][64 col][4 ti]
    __shared__ float hs[16];

    const int lane = threadIdx.x;
    const int u    = lane & 15;
    const int quad = lane >> 4;
    const int col  = quad * 16 + u;
    const int b    = blockIdx.x;
    const float NL2E = -1.4426950408889634f;     // -log2(e)
    const float sg   = (quad == 2) ? 1.0f : NL2E;

    // ---- Wh column, rows permuted to match whatever row_ror:m delivers ----
    float w[16];
    w[0] = Wh[(size_t)u * 64 + col] * sg;
#define WL(M) { int ii_; RORI(M, ii_, u); w[M] = Wh[(size_t)ii_ * 64 + col] * sg; }
    WL(1)  WL(2)  WL(3)  WL(4)  WL(5)  WL(6)  WL(7)
    WL(8)  WL(9)  WL(10) WL(11) WL(12) WL(13) WL(14) WL(15)
#undef WL

    // ---- Wx as MFMA B-frags (gate-scaled), bias ----
    // B[k = quad*8+e + kc*32][n = u] = Wx[f][nt*16+u] * s(nt)
    bf16x8 wxf[4][2];
    float bv[4];
    #pragma unroll
    for (int nt = 0; nt < 4; ++nt) {
        const float s = (nt == 2) ? 1.0f : NL2E;
        #pragma unroll
        for (int kc = 0; kc < 2; ++kc)
            #pragma unroll
            for (int e = 0; e < 8; ++e)
                wxf[nt][kc][e] = (short)f2bf(
                    Wx[(size_t)(kc * 32 + quad * 8 + e) * 64 + nt * 16 + u] * s);
        bv[nt] = bias[nt * 16 + u] * s;
    }

    // ---- x tile registers, ping-pong (statically indexed) ----
    f32x4 xa0[4], xa1[4];
    auto xload = [&](int tile, f32x4 (&xs)[4]) {
        const float* p = x + ((size_t)b * Tdim + tile * 16 + u) * 64 + quad * 8;
        xs[0] = *(const f32x4*)(p);
        xs[1] = *(const f32x4*)(p + 4);
        xs[2] = *(const f32x4*)(p + 32);
        xs[3] = *(const f32x4*)(p + 36);
    };

    // A[m = u (timestep)][k = quad*8+e + kc*32] = x[b][t0+u][f]
    // D[m = t][n = col16] -> store f32x4 over reg dim = ti at
    // zbuf[buf][tb=quad][col=nt*16+u][0..3]   (bank-uniform)
    auto proj = [&](const f32x4 (&xs)[4], int buf) {
        U32x4 af[2];
        #pragma unroll
        for (int kc = 0; kc < 2; ++kc) {
            asm("v_cvt_pk_bf16_f32 %0, %1, %2" : "=v"(af[kc].u[0]) : "v"(xs[2*kc][0]),   "v"(xs[2*kc][1]));
            asm("v_cvt_pk_bf16_f32 %0, %1, %2" : "=v"(af[kc].u[1]) : "v"(xs[2*kc][2]),   "v"(xs[2*kc][3]));
            asm("v_cvt_pk_bf16_f32 %0, %1, %2" : "=v"(af[kc].u[2]) : "v"(xs[2*kc+1][0]), "v"(xs[2*kc+1][1]));
            asm("v_cvt_pk_bf16_f32 %0, %1, %2" : "=v"(af[kc].u[3]) : "v"(xs[2*kc+1][2]), "v"(xs[2*kc+1][3]));
        }
        float* zb = zbuf + buf * 1024 + quad * 256 + u * 4;
        #pragma unroll
        for (int nt = 0; nt < 4; ++nt) {
            f32x4 a = {bv[nt], bv[nt], bv[nt], bv[nt]};
            a = __builtin_amdgcn_mfma_f32_16x16x32_bf16(af[0].v, wxf[nt][0], a, 0, 0, 0);
            a = __builtin_amdgcn_mfma_f32_16x16x32_bf16(af[1].v, wxf[nt][1], a, 0, 0, 0);
            *(f32x4*)(zb + nt * 64) = a;
        }
    };

    // ---- prologue ----
    xload(0, xa0);
    proj(xa0, 0);
    xload(1, xa1);

    float c = 0.f, h = 0.f;
    f32x4 zgA = *(const f32x4*)(zbuf + col * 4);   // group 0 (buf0, tb0)
    f32x4 zgB;

    const bool q0 = (lane & 16) != 0;
    const bool q1 = (lane & 32) != 0;
    const bool isrelu = (quad == 2);

    auto scan_tile = [&](int n) {
        #pragma unroll
        for (int t = 0; t < 16; ++t) {
            const int gl = t >> 2;
            if ((t & 3) == 0) {            // prefetch z group gl+1 (4 steps out)
                const int gg = n * 4 + gl + 1;
                if (gg < 4 * NTILE) {
                    const float* zp = zbuf + ((gg >> 2) & 1) * 1024
                                    + (gg & 3) * 256 + col * 4;
                    f32x4 zv = *(const f32x4*)zp;
                    if (gl & 1) zgA = zv; else zgB = zv;
                }
            }
            const float zval = (gl & 1) ? zgB[t & 3] : zgA[t & 3];

            // recurrent dot: acc = z + sum_k h[k]*Wh[k][col] (pre-scaled)
            float acc0 = fmaf(h, w[0], zval), acc1 = 0.f, hr;
#define DOT(M, A_) { RORF(M, hr, h); A_ = fmaf(hr, w[M], A_); }
            DOT(1,  acc1) DOT(2,  acc0) DOT(3,  acc1) DOT(4,  acc0)
            DOT(5,  acc1) DOT(6,  acc0) DOT(7,  acc1) DOT(8,  acc0)
            DOT(9,  acc1) DOT(10, acc0) DOT(11, acc1) DOT(12, acc0)
            DOT(13, acc1) DOT(14, acc0) DOT(15, acc1)
#undef DOT
            const float zacc = acc0 + acc1;

            // activation (sigmoid lanes hold -z*log2e): sig = rcp(1+2^w)
            const float sig = __builtin_amdgcn_rcpf(1.0f + fast_exp2(zacc));
            const float a   = isrelu ? fmaxf(zacc, 0.0f) : sig;

            // gather the 4 gates of unit u across quads
            const float a16 = __shfl_xor(a, 16, 64);
            const float a32 = __shfl_xor(a, 32, 64);
            const float a48 = __shfl_xor(a16, 32, 64);
            // b[m] = activation of gate (quad ^ m); select roles i,f,g,o
            const float A1 = q0 ? a16 : a;      // b[q&1]
            const float B1 = q0 ? a48 : a32;    // b[2|(q&1)]
            const float A2 = q0 ? a   : a16;    // b[(q&1)^1]
            const float B2 = q0 ? a32 : a48;    // b[2|((q&1)^1)]
            const float gi = q1 ? B1 : A1;      // gate 0 (i)
            const float gG = q1 ? A1 : B1;      // gate 2 (g, relu'd)
            const float gf = q1 ? B2 : A2;      // gate 1 (f)
            const float go = q1 ? A2 : B2;      // gate 3 (o)

            c = fmaf(gf, c, gi * gG);
            h = go * fmaxf(c, 0.0f);            // h = o * relu(c_new)
        }
    };

    // ---- main loop: unroll-by-2 so xa ping-pong stays statically indexed ----
    #pragma unroll 1
    for (int nn = 0; nn < NTILE / 2; ++nn) {
        {
            const int n = 2 * nn;               // even tile: proj n+1 -> buf1
            if (n + 2 < NTILE) xload(n + 2, xa0);
            proj(xa1, 1);
            scan_tile(n);
        }
        {
            const int n = 2 * nn + 1;           // odd tile: proj n+1 -> buf0
            if (n + 2 < NTILE) xload(n + 2, xa1);
            if (n + 1 < NTILE) proj(xa0, 0);
            scan_tile(n);
        }
    }

    // ---- MLP head (single wave: DS in-order, no barrier) ----
    if (lane < 16) hs[lane] = h;                // quad0 lanes: h[u]
    if (lane == 0) {
        float x2[8];
        #pragma unroll
        for (int k = 0; k < 8; ++k) {
            float s = b2[k];
            #pragma unroll
            for (int q = 0; q < 16; ++q) s = fmaf(hs[q], W2[(size_t)q * 8 + k], s);
            x2[k] = fmaxf(s, 0.f);
        }
        float x3[4];
        #pragma unroll
        for (int m = 0; m < 4; ++m) {
            float s = b3[m];
            #pragma unroll
            for (int k = 0; k < 8; ++k) s = fmaf(x2[k], W3[(size_t)k * 4 + m], s);
            x3[m] = fmaxf(s, 0.f);
        }
        float s = bo[0];
        #pragma unroll
        for (int m = 0; m < 4; ++m) s = fmaf(x3[m], Wo[m], s);
        out[b] = sigmoidf(s);
    }
}

extern "C" void kernel_launch(void* const* d_in, const int* in_sizes, int n_in,
                              void* d_out, int out_size, void* d_ws, size_t ws_size,
                              hipStream_t stream) {
    const float* x  = (const float*)d_in[0];
    const float* Wx = (const float*)d_in[1];
    const float* Wh = (const float*)d_in[2];
    const float* bb = (const float*)d_in[3];
    const float* W2 = (const float*)d_in[4];
    const float* b2 = (const float*)d_in[5];
    const float* W3 = (const float*)d_in[6];
    const float* b3 = (const float*)d_in[7];
    const float* Wo = (const float*)d_in[8];
    const float* bo = (const float*)d_in[9];

    // One batch row per single-wave block: 2048 blocks -> 8 waves/CU.
    lstm_fused<<<Bdim, 64, 0, stream>>>(x, Wx, bb, Wh, W2, b2, W3, b3,
                                        Wo, bo, (float*)d_out);
}

// Round 5
// 381.192 us; speedup vs baseline: 1.1876x; 1.1149x over previous
//
#include <hip/hip_runtime.h>
#include <stdint.h>

// Problem dims (fixed by the reference): B=2048, T=512, F=64, H=16, 4H=64.
#define Bdim 2048
#define Tdim 512
#define NTILE 32                 // 32 tiles of 16 timesteps

typedef __attribute__((ext_vector_type(8))) short bf16x8;   // 8 bf16, 4 VGPRs
typedef __attribute__((ext_vector_type(4))) float f32x4;

union U32x4 { uint32_t u[4]; bf16x8 v; };

__device__ __forceinline__ uint16_t f2bf(float f) {
    union { float f; uint32_t u; } v; v.f = f;
    uint32_t r = v.u + 0x7fffu + ((v.u >> 16) & 1u);
    return (uint16_t)(r >> 16);
}
__device__ __forceinline__ float sigmoidf(float z) {
    return __builtin_amdgcn_rcpf(1.0f + __expf(-z));
}
__device__ __forceinline__ float fast_exp2(float x) {
#if __has_builtin(__builtin_amdgcn_exp2f)
    return __builtin_amdgcn_exp2f(x);
#else
    return exp2f(x);
#endif
}

// Init-time probe: which source index does row_ror:M deliver to this lane?
// (same DPP control 0x120|M as the asm fmac below -> direction-proof)
#define RORI(M, dst, src)                                                     \
    dst = __builtin_amdgcn_update_dpp((src), (src), 0x120 | (M), 0xF, 0xF, 0)

// Rotate-fused FMA: acc += row_ror:M(h) * w[M]  -- ONE VALU instruction.
// DPP applies to src0 (h). Hazard (VALU write of h -> DPP read) is guarded
// by an s_nop pinned between the h-producer and these via a "+v"(h) dep.
#define FMAC_ROR(M, ACC)                                                      \
    asm("v_fmac_f32 %0, %1, %2 row_ror:" #M " row_mask:0xf bank_mask:0xf"     \
        : "+v"(ACC) : "v"(h), "v"(w[M]))

// 2048 single-wave blocks, one batch row per wave (8 waves/CU, no barriers).
// Lane (quad g, u = lane&15) owns gate g of hidden unit u (col = g*16+u).
// Per step (~27 VALU, 2 trans, 4 parallel DS):
//   - recurrent dot: 1 fmaf + 15 rotate-fused v_fmac_f32_dpp (h distributed:
//     lane holds h[u], identical across the 4 quads)
//   - activation: sigmoid lanes pre-scaled by -log2e -> rcp(1+exp2(acc))
//   - gate gather: 4 independent ds_bpermute with precomputed addresses
//     (gate g of unit u lives in lane 16g+u); c,h updated replicated in
//     all quads (bit-identical)
// xz = x@Wx + b is produced per-wave by MFMA (A = 16-timestep x tile,
// B = Wx frags) into a double-buffered LDS tile laid out [tb][col][4] so both
// the b128 store and the 1-read-per-4-steps are bank-uniform.
__global__ __launch_bounds__(64, 2) void lstm_fused(
    const float* __restrict__ x, const float* __restrict__ Wx,
    const float* __restrict__ bias, const float* __restrict__ Wh,
    const float* __restrict__ W2, const float* __restrict__ b2,
    const float* __restrict__ W3, const float* __restrict__ b3,
    const float* __restrict__ Wo, const float* __restrict__ bo,
    float* __restrict__ out)
{
    __shared__ __align__(16) float zbuf[2048];   // [2 buf][4 tb][64 col][4 ti]
    __shared__ float hs[16];

    const int lane = threadIdx.x;
    const int u    = lane & 15;
    const int quad = lane >> 4;
    const int col  = quad * 16 + u;
    const int b    = blockIdx.x;
    const float NL2E = -1.4426950408889634f;     // -log2(e)
    const float sg   = (quad == 2) ? 1.0f : NL2E;

    // ---- Wh column, rows permuted to match whatever row_ror:m delivers ----
    float w[16];
    w[0] = Wh[(size_t)u * 64 + col] * sg;
#define WL(M) { int ii_; RORI(M, ii_, u); w[M] = Wh[(size_t)ii_ * 64 + col] * sg; }
    WL(1)  WL(2)  WL(3)  WL(4)  WL(5)  WL(6)  WL(7)
    WL(8)  WL(9)  WL(10) WL(11) WL(12) WL(13) WL(14) WL(15)
#undef WL

    // ---- gate-gather bpermute addresses (loop-invariant) ----
    const int adr_i = (u +  0) * 4;
    const int adr_f = (u + 16) * 4;
    const int adr_g = (u + 32) * 4;
    const int adr_o = (u + 48) * 4;

    // ---- Wx as MFMA B-frags (gate-scaled), bias ----
    // B[k = quad*8+e + kc*32][n = u] = Wx[f][nt*16+u] * s(nt)
    bf16x8 wxf[4][2];
    float bv[4];
    #pragma unroll
    for (int nt = 0; nt < 4; ++nt) {
        const float s = (nt == 2) ? 1.0f : NL2E;
        #pragma unroll
        for (int kc = 0; kc < 2; ++kc)
            #pragma unroll
            for (int e = 0; e < 8; ++e)
                wxf[nt][kc][e] = (short)f2bf(
                    Wx[(size_t)(kc * 32 + quad * 8 + e) * 64 + nt * 16 + u] * s);
        bv[nt] = bias[nt * 16 + u] * s;
    }

    // ---- x tile registers, ping-pong (statically indexed) ----
    f32x4 xa0[4], xa1[4];
    auto xload = [&](int tile, f32x4 (&xs)[4]) {
        const float* p = x + ((size_t)b * Tdim + tile * 16 + u) * 64 + quad * 8;
        xs[0] = *(const f32x4*)(p);
        xs[1] = *(const f32x4*)(p + 4);
        xs[2] = *(const f32x4*)(p + 32);
        xs[3] = *(const f32x4*)(p + 36);
    };

    // A[m = u (timestep)][k = quad*8+e + kc*32] = x[b][t0+u][f]
    // D[m = t][n = col16] -> store f32x4 over reg dim = ti at
    // zbuf[buf][tb=quad][col=nt*16+u][0..3]   (bank-uniform)
    auto proj = [&](const f32x4 (&xs)[4], int buf) {
        U32x4 af[2];
        #pragma unroll
        for (int kc = 0; kc < 2; ++kc) {
            asm("v_cvt_pk_bf16_f32 %0, %1, %2" : "=v"(af[kc].u[0]) : "v"(xs[2*kc][0]),   "v"(xs[2*kc][1]));
            asm("v_cvt_pk_bf16_f32 %0, %1, %2" : "=v"(af[kc].u[1]) : "v"(xs[2*kc][2]),   "v"(xs[2*kc][3]));
            asm("v_cvt_pk_bf16_f32 %0, %1, %2" : "=v"(af[kc].u[2]) : "v"(xs[2*kc+1][0]), "v"(xs[2*kc+1][1]));
            asm("v_cvt_pk_bf16_f32 %0, %1, %2" : "=v"(af[kc].u[3]) : "v"(xs[2*kc+1][2]), "v"(xs[2*kc+1][3]));
        }
        float* zb = zbuf + buf * 1024 + quad * 256 + u * 4;
        #pragma unroll
        for (int nt = 0; nt < 4; ++nt) {
            f32x4 a = {bv[nt], bv[nt], bv[nt], bv[nt]};
            a = __builtin_amdgcn_mfma_f32_16x16x32_bf16(af[0].v, wxf[nt][0], a, 0, 0, 0);
            a = __builtin_amdgcn_mfma_f32_16x16x32_bf16(af[1].v, wxf[nt][1], a, 0, 0, 0);
            *(f32x4*)(zb + nt * 64) = a;
        }
    };

    // ---- prologue ----
    xload(0, xa0);
    proj(xa0, 0);
    xload(1, xa1);

    float c = 0.f, h = 0.f;
    f32x4 zgA = *(const f32x4*)(zbuf + col * 4);   // group 0 (buf0, tb0)
    f32x4 zgB;

    const bool isrelu = (quad == 2);

    auto scan_tile = [&](int n) {
        // static prefetch bases for this tile (offsets fold to immediates)
        const float* curp = zbuf + (n & 1) * 1024 + col * 4;
        const float* othp = zbuf + ((n & 1) ^ 1) * 1024 + col * 4;
        #pragma unroll
        for (int t = 0; t < 16; ++t) {
            const int gl = t >> 2;
            if ((t & 3) == 0) {
                // prefetch z group gl+1 (4 steps out); at the last tile the
                // gl=3 prefetch reads in-bounds stale data that is never used
                const float* zp = (gl < 3) ? (curp + (gl + 1) * 256) : othp;
                f32x4 zv = *(const f32x4*)zp;
                if (gl & 1) zgA = zv; else zgB = zv;
            }
            const float zval = (gl & 1) ? zgB[t & 3] : zgA[t & 3];

            // DPP hazard fence: >=2 cycles between h's producer and the
            // rotate-fused fmacs below (data-dep pins the order).
            asm volatile("s_nop 1" : "+v"(h));

            // recurrent dot: acc = z + sum_k h[k]*Wh[k][col] (pre-scaled)
            float acc0 = fmaf(h, w[0], zval);
            float acc1 = 0.f;
            FMAC_ROR(1,  acc1); FMAC_ROR(2,  acc0); FMAC_ROR(3,  acc1);
            FMAC_ROR(4,  acc0); FMAC_ROR(5,  acc1); FMAC_ROR(6,  acc0);
            FMAC_ROR(7,  acc1); FMAC_ROR(8,  acc0); FMAC_ROR(9,  acc1);
            FMAC_ROR(10, acc0); FMAC_ROR(11, acc1); FMAC_ROR(12, acc0);
            FMAC_ROR(13, acc1); FMAC_ROR(14, acc0); FMAC_ROR(15, acc1);
            const float zacc = acc0 + acc1;

            // activation (sigmoid lanes hold -z*log2e): sig = rcp(1+2^w)
            const float sig = __builtin_amdgcn_rcpf(1.0f + fast_exp2(zacc));
            const float a   = isrelu ? fmaxf(zacc, 0.0f) : sig;

            // gather the 4 gates of unit u: 4 independent bpermutes,
            // precomputed addresses, zero VALU
            const int ia = __float_as_int(a);
            const float gi = __int_as_float(__builtin_amdgcn_ds_bpermute(adr_i, ia));
            const float gf = __int_as_float(__builtin_amdgcn_ds_bpermute(adr_f, ia));
            const float gG = __int_as_float(__builtin_amdgcn_ds_bpermute(adr_g, ia));
            const float go = __int_as_float(__builtin_amdgcn_ds_bpermute(adr_o, ia));

            c = fmaf(gf, c, gi * gG);
            h = go * fmaxf(c, 0.0f);            // h = o * relu(c_new)
        }
    };

    // ---- main loop: unroll-by-2 so xa ping-pong stays statically indexed ----
    #pragma unroll 1
    for (int nn = 0; nn < NTILE / 2; ++nn) {
        {
            const int n = 2 * nn;               // even tile: proj n+1 -> buf1
            if (n + 2 < NTILE) xload(n + 2, xa0);
            proj(xa1, 1);
            scan_tile(n);
        }
        {
            const int n = 2 * nn + 1;           // odd tile: proj n+1 -> buf0
            if (n + 2 < NTILE) xload(n + 2, xa1);
            if (n + 1 < NTILE) proj(xa0, 0);
            scan_tile(n);
        }
    }

    // ---- MLP head (single wave: DS in-order, no barrier) ----
    if (lane < 16) hs[lane] = h;                // quad0 lanes: h[u]
    if (lane == 0) {
        float x2[8];
        #pragma unroll
        for (int k = 0; k < 8; ++k) {
            float s = b2[k];
            #pragma unroll
            for (int q = 0; q < 16; ++q) s = fmaf(hs[q], W2[(size_t)q * 8 + k], s);
            x2[k] = fmaxf(s, 0.f);
        }
        float x3[4];
        #pragma unroll
        for (int m = 0; m < 4; ++m) {
            float s = b3[m];
            #pragma unroll
            for (int k = 0; k < 8; ++k) s = fmaf(x2[k], W3[(size_t)k * 4 + m], s);
            x3[m] = fmaxf(s, 0.f);
        }
        float s = bo[0];
        #pragma unroll
        for (int m = 0; m < 4; ++m) s = fmaf(x3[m], Wo[m], s);
        out[b] = sigmoidf(s);
    }
}

extern "C" void kernel_launch(void* const* d_in, const int* in_sizes, int n_in,
                              void* d_out, int out_size, void* d_ws, size_t ws_size,
                              hipStream_t stream) {
    const float* x  = (const float*)d_in[0];
    const float* Wx = (const float*)d_in[1];
    const float* Wh = (const float*)d_in[2];
    const float* bb = (const float*)d_in[3];
    const float* W2 = (const float*)d_in[4];
    const float* b2 = (const float*)d_in[5];
    const float* W3 = (const float*)d_in[6];
    const float* b3 = (const float*)d_in[7];
    const float* Wo = (const float*)d_in[8];
    const float* bo = (const float*)d_in[9];

    // One batch row per single-wave block: 2048 blocks -> 8 waves/CU.
    lstm_fused<<<Bdim, 64, 0, stream>>>(x, Wx, bb, Wh, W2, b2, W3, b3,
                                        Wo, bo, (float*)d_out);
}